// Round 1
// baseline (413.241 us; speedup 1.0000x reference)
//
#include <hip/hip_runtime.h>

// Problem constants
constexpr int N = 4096, E = 131072, F = 64, HID = 64, OUTF = 86, NB = 16, HEADS = 4, DH = 16;
constexpr int NSPLIT = 8;   // KV splits for flash attention (occupancy)
constexpr int KT = 128;     // key tile size (LDS)
constexpr int QT = 256;     // queries per block (1 per thread)

// Workspace layout (offsets in floats)
constexpr size_t OFF_DEG   = 0;                                     // N
constexpr size_t OFF_DIS   = OFF_DEG + N;                           // N
constexpr size_t OFF_BUFA  = OFF_DIS + N;                           // N*64: xW1, later o@Wout
constexpr size_t OFF_BUFB  = OFF_BUFA + (size_t)N * 64;             // N*64: agg1/h1, later o
constexpr size_t OFF_QKV   = OFF_BUFB + (size_t)N * 64;             // N*192: qkv, later h2pre (N*86)
constexpr size_t OFF_OPART = OFF_QKV + (size_t)N * 192;             // HEADS*N*NSPLIT*DH
constexpr size_t OFF_MPART = OFF_OPART + (size_t)HEADS * N * NSPLIT * DH;
constexpr size_t OFF_LPART = OFF_MPART + (size_t)HEADS * N * NSPLIT;
constexpr size_t OFF_H2AGG = OFF_OPART;                             // reuse after combine (N*86)

// ---------------- degree / norm ----------------
__global__ void deg_kernel(const int* __restrict__ ei, const float* __restrict__ ea,
                           float* __restrict__ deg) {
    int i = blockIdx.x * blockDim.x + threadIdx.x;
    if (i < E) {
        atomicAdd(&deg[ei[E + i]], ea[i]);          // dst = edge_index[1][e]
    } else if (i < E + N) {
        atomicAdd(&deg[i - E], 1.0f);               // self-loop weight 1
    }
}

__global__ void dis_kernel(float* __restrict__ deg, float* __restrict__ dis) {
    int i = blockIdx.x * blockDim.x + threadIdx.x;
    if (i < N) {
        float d = deg[i];
        dis[i] = d > 0.0f ? rsqrtf(fmaxf(d, 1e-12f)) : 0.0f;
    }
}

// ---------------- small GEMM: C[M,NOUT] = A[M,64] @ W[NOUT,64]^T (+bias) ----------------
template <int NOUT>
__global__ __launch_bounds__(256) void gemm_kernel(const float* __restrict__ A,
                                                   const float* __restrict__ W,
                                                   const float* __restrict__ bias,
                                                   float* __restrict__ C) {
    __shared__ float Ws[NOUT * 65];   // padded stride 65: conflict-free reads
    __shared__ float As[16 * 64];
    int row0 = blockIdx.x * 16;
    for (int idx = threadIdx.x; idx < NOUT * 64; idx += 256) {
        int c = idx >> 6, k = idx & 63;
        Ws[c * 65 + k] = W[idx];      // coalesced global, conflict-free LDS write
    }
    for (int idx = threadIdx.x; idx < 16 * 64; idx += 256)
        As[idx] = A[(size_t)row0 * 64 + idx];
    __syncthreads();
    for (int idx = threadIdx.x; idx < 16 * NOUT; idx += 256) {
        int r = idx / NOUT, c = idx - r * NOUT;
        float acc = bias ? bias[c] : 0.0f;
#pragma unroll
        for (int k = 0; k < 64; ++k) acc += As[r * 64 + k] * Ws[c * 65 + k];
        C[(size_t)(row0 + r) * NOUT + c] = acc;
    }
}

// ---------------- GCN aggregation: agg[dst] += norm * H[src], one wave per edge ----------------
template <int FD>
__global__ void agg_kernel(const int* __restrict__ ei, const float* __restrict__ ea,
                           const float* __restrict__ dis, const float* __restrict__ Hin,
                           float* __restrict__ Agg) {
    int wid = (blockIdx.x * blockDim.x + threadIdx.x) >> 6;
    int lane = threadIdx.x & 63;
    if (wid >= E + N) return;
    int s, d; float w;
    if (wid < E) { s = ei[wid]; d = ei[E + wid]; w = ea[wid]; }
    else         { s = d = wid - E; w = 1.0f; }
    float norm = dis[s] * w * dis[d];
    for (int f = lane; f < FD; f += 64)
        atomicAdd(&Agg[(size_t)d * FD + f], norm * Hin[(size_t)s * FD + f]);
}

// ---------------- bias + relu (in place) ----------------
__global__ void bias_relu_kernel(float* __restrict__ h, const float* __restrict__ b) {
    int i = blockIdx.x * blockDim.x + threadIdx.x;
    if (i < N * 64) h[i] = fmaxf(h[i] + b[i & 63], 0.0f);
}

// ---------------- flash attention (fp32, KV-split partials) ----------------
__global__ __launch_bounds__(256) void attn_kernel(const float* __restrict__ qkv,
                                                   float* __restrict__ o_part,
                                                   float* __restrict__ m_part,
                                                   float* __restrict__ l_part) {
    // grid: (N/QT, HEADS, NSPLIT), block 256 = one query per thread
    int qi = blockIdx.x * QT + threadIdx.x;
    int h  = blockIdx.y;
    int sp = blockIdx.z;
    __shared__ float Ks[KT][DH];
    __shared__ float Vs[KT][DH];

    float q[DH];
#pragma unroll
    for (int d = 0; d < DH; ++d) q[d] = qkv[(size_t)qi * 192 + h * DH + d] * 0.25f; // 1/sqrt(16)

    float o[DH];
#pragma unroll
    for (int d = 0; d < DH; ++d) o[d] = 0.0f;
    float m = -1e30f, l = 0.0f;

    int k0 = sp * (N / NSPLIT);
    for (int kt = 0; kt < N / NSPLIT; kt += KT) {
        __syncthreads();
        for (int idx = threadIdx.x; idx < KT * DH; idx += 256) {
            int j = idx / DH, d = idx - j * DH;
            int key = k0 + kt + j;
            Ks[j][d] = qkv[(size_t)key * 192 + 64  + h * DH + d];
            Vs[j][d] = qkv[(size_t)key * 192 + 128 + h * DH + d];
        }
        __syncthreads();
#pragma unroll 2
        for (int j = 0; j < KT; ++j) {
            float s0 = 0.f, s1 = 0.f;
#pragma unroll
            for (int d = 0; d < DH; d += 2) {
                s0 += q[d]     * Ks[j][d];
                s1 += q[d + 1] * Ks[j][d + 1];
            }
            float s = s0 + s1;
            if (s <= m) {                       // common path: max unchanged
                float p = __expf(s - m);
                l += p;
#pragma unroll
                for (int d = 0; d < DH; ++d) o[d] += p * Vs[j][d];
            } else {                            // rare: new max, rescale
                float corr = __expf(m - s);
                m = s;
                l = l * corr + 1.0f;
#pragma unroll
                for (int d = 0; d < DH; ++d) o[d] = o[d] * corr + Vs[j][d];
            }
        }
    }
    size_t pidx = ((size_t)h * N + qi) * NSPLIT + sp;
    m_part[pidx] = m;
    l_part[pidx] = l;
#pragma unroll
    for (int d = 0; d < DH; ++d) o_part[pidx * DH + d] = o[d];
}

__global__ void combine_kernel(const float* __restrict__ o_part, const float* __restrict__ m_part,
                               const float* __restrict__ l_part, float* __restrict__ o) {
    int t = blockIdx.x * blockDim.x + threadIdx.x;
    if (t >= HEADS * N) return;
    int h = t / N, qi = t - h * N;
    size_t base = ((size_t)h * N + qi) * NSPLIT;
    float M = -1e30f;
#pragma unroll
    for (int s = 0; s < NSPLIT; ++s) M = fmaxf(M, m_part[base + s]);
    float L = 0.0f;
    float acc[DH];
#pragma unroll
    for (int d = 0; d < DH; ++d) acc[d] = 0.0f;
#pragma unroll
    for (int s = 0; s < NSPLIT; ++s) {
        float c = __expf(m_part[base + s] - M);
        L += c * l_part[base + s];
#pragma unroll
        for (int d = 0; d < DH; ++d) acc[d] += c * o_part[(base + s) * DH + d];
    }
    float inv = 1.0f / L;
#pragma unroll
    for (int d = 0; d < DH; ++d) o[(size_t)qi * 64 + h * DH + d] = acc[d] * inv;
}

// ---------------- pooled mean per graph (batch sorted) ----------------
__global__ void pool_kernel(const float* __restrict__ h2, const int* __restrict__ batch,
                            const float* __restrict__ b2, float* __restrict__ out) {
    int b = blockIdx.x;
    // lower_bound(batch, b) and lower_bound(batch, b+1)
    int lo = 0, hi = N;
    while (lo < hi) { int mid = (lo + hi) >> 1; if (batch[mid] < b) lo = mid + 1; else hi = mid; }
    int start = lo;
    lo = start; hi = N;
    while (lo < hi) { int mid = (lo + hi) >> 1; if (batch[mid] < b + 1) lo = mid + 1; else hi = mid; }
    int end = lo;
    int f = threadIdx.x;
    if (f >= OUTF) return;
    float acc = 0.0f;
    for (int i = start; i < end; ++i) acc += h2[(size_t)i * OUTF + f];
    if (end > start)
        out[b * OUTF + f] = acc / (float)(end - start) + b2[f];
    else
        out[b * OUTF + f] = 0.0f;
}

extern "C" void kernel_launch(void* const* d_in, const int* in_sizes, int n_in,
                              void* d_out, int out_size, void* d_ws, size_t ws_size,
                              hipStream_t stream) {
    const float* x     = (const float*)d_in[0];
    const int*   ei    = (const int*)  d_in[1];
    const float* ea    = (const float*)d_in[2];
    const int*   batch = (const int*)  d_in[3];
    const float* W1    = (const float*)d_in[4];
    const float* b1    = (const float*)d_in[5];
    const float* Win   = (const float*)d_in[6];
    const float* b_in  = (const float*)d_in[7];
    const float* Wout  = (const float*)d_in[8];
    const float* b_out = (const float*)d_in[9];
    const float* W2    = (const float*)d_in[10];
    const float* b2    = (const float*)d_in[11];
    float* out = (float*)d_out;
    float* ws  = (float*)d_ws;

    float* deg   = ws + OFF_DEG;
    float* dis   = ws + OFF_DIS;
    float* bufA  = ws + OFF_BUFA;   // xW1, later o@Wout
    float* bufB  = ws + OFF_BUFB;   // agg1/h1, later o
    float* qkv   = ws + OFF_QKV;    // qkv, later h2pre
    float* opart = ws + OFF_OPART;
    float* mpart = ws + OFF_MPART;
    float* lpart = ws + OFF_LPART;
    float* h2agg = ws + OFF_H2AGG;

    // degree + norm
    hipMemsetAsync(deg, 0, (size_t)N * 4, stream);
    deg_kernel<<<(E + N + 255) / 256, 256, 0, stream>>>(ei, ea, deg);
    dis_kernel<<<(N + 255) / 256, 256, 0, stream>>>(deg, dis);

    // GCN1: xW1 -> aggregate -> +b1, relu
    gemm_kernel<64><<<N / 16, 256, 0, stream>>>(x, W1, nullptr, bufA);
    hipMemsetAsync(bufB, 0, (size_t)N * 64 * 4, stream);
    {
        int waves = E + N;
        int blocks = (waves * 64 + 255) / 256;
        agg_kernel<64><<<blocks, 256, 0, stream>>>(ei, ea, dis, bufA, bufB);
    }
    bias_relu_kernel<<<(N * 64 + 255) / 256, 256, 0, stream>>>(bufB, b1);

    // QKV projection
    gemm_kernel<192><<<N / 16, 256, 0, stream>>>(bufB, Win, b_in, qkv);

    // flash attention with KV splits, then combine into bufB (=o, [N,64])
    attn_kernel<<<dim3(N / QT, HEADS, NSPLIT), 256, 0, stream>>>(qkv, opart, mpart, lpart);
    combine_kernel<<<(HEADS * N + 255) / 256, 256, 0, stream>>>(opart, mpart, lpart, bufB);

    // output projection: bufA = o @ Wout^T + b_out
    gemm_kernel<64><<<N / 16, 256, 0, stream>>>(bufB, Wout, b_out, bufA);

    // GCN2: h2pre = bufA @ W2^T (reuse qkv buffer), aggregate (bias folded into pool)
    gemm_kernel<86><<<N / 16, 256, 0, stream>>>(bufA, W2, nullptr, qkv);
    hipMemsetAsync(h2agg, 0, (size_t)N * 86 * 4, stream);
    {
        int waves = E + N;
        int blocks = (waves * 64 + 255) / 256;
        agg_kernel<86><<<blocks, 256, 0, stream>>>(ei, ea, dis, qkv, h2agg);
    }

    // pooled mean + b2
    pool_kernel<<<NB, 128, 0, stream>>>(h2agg, batch, b2, out);
}

// Round 2
// 337.978 us; speedup vs baseline: 1.2227x; 1.2227x over previous
//
#include <hip/hip_runtime.h>

// Problem constants
constexpr int N = 4096, E = 131072, F = 64, HID = 64, OUTF = 86, NB = 16, HEADS = 4, DH = 16;
constexpr int NSPLIT = 16;  // KV splits for flash attention
constexpr int KT = 256;     // key tile per block == N/NSPLIT (single tile)

// Workspace layout (offsets in float units; all 16B-aligned)
constexpr size_t OFF_DEG   = 0;                    // N floats
constexpr size_t OFF_CNT   = OFF_DEG + N;          // N ints (counts)
constexpr size_t OFF_CUR   = OFF_CNT + N;          // N ints (fill cursors)
constexpr size_t OFF_DIS   = OFF_CUR + N;          // N floats
constexpr size_t OFF_ROW   = OFF_DIS + N;          // N+16 ints (rowstart)
constexpr size_t OFF_CSRC  = OFF_ROW + N + 16;     // E ints  (csr src)
constexpr size_t OFF_CNRM  = OFF_CSRC + E;         // E floats (csr norm)
constexpr size_t OFF_BUFA  = OFF_CNRM + E;         // N*64: xW1, later o@Wout
constexpr size_t OFF_BUFB  = OFF_BUFA + (size_t)N * 64;   // N*64: h1, later o
constexpr size_t OFF_QKV   = OFF_BUFB + (size_t)N * 64;   // N*192: qkv, later h2pre (N*86)
constexpr size_t OFF_OPART = OFF_QKV + (size_t)N * 192;   // HEADS*N*NSPLIT*DH
constexpr size_t OFF_MPART = OFF_OPART + (size_t)HEADS * N * NSPLIT * DH;
constexpr size_t OFF_LPART = OFF_MPART + (size_t)HEADS * N * NSPLIT;
constexpr size_t OFF_H2AGG = OFF_OPART;            // reuse after combine (N*86)

// ---------------- CSR build: histogram (+weighted degree) ----------------
__global__ void hist_kernel(const int* __restrict__ ei, const float* __restrict__ ea,
                            float* __restrict__ deg, int* __restrict__ counts) {
    int i = blockIdx.x * blockDim.x + threadIdx.x;
    if (i < E) {
        int d = ei[E + i];
        atomicAdd(&deg[d], ea[i]);
        atomicAdd(&counts[d], 1);
    }
}

// single block, 1024 threads: exclusive scan of counts -> rowstart; dis = rsqrt(deg+1)
__global__ __launch_bounds__(1024) void scan_dis_kernel(const int* __restrict__ counts,
                                                        const float* __restrict__ deg,
                                                        int* __restrict__ rowstart,
                                                        float* __restrict__ dis) {
    __shared__ int sums[1024];
    int t = threadIdx.x;
    int c[4];
    int base = t * 4;
    int s = 0;
#pragma unroll
    for (int k = 0; k < 4; ++k) { c[k] = counts[base + k]; s += c[k]; }
    sums[t] = s;
    __syncthreads();
    for (int off = 1; off < 1024; off <<= 1) {
        int v = (t >= off) ? sums[t - off] : 0;
        __syncthreads();
        sums[t] += v;
        __syncthreads();
    }
    int run = (t > 0) ? sums[t - 1] : 0;
#pragma unroll
    for (int k = 0; k < 4; ++k) { rowstart[base + k] = run; run += c[k]; }
    if (t == 1023) rowstart[N] = run;
    for (int i = t; i < N; i += 1024) dis[i] = rsqrtf(deg[i] + 1.0f);  // +1 = self-loop; always > 0
}

__global__ void fill_kernel(const int* __restrict__ ei, const float* __restrict__ ea,
                            const float* __restrict__ dis, const int* __restrict__ rowstart,
                            int* __restrict__ cursor, int* __restrict__ csr_src,
                            float* __restrict__ csr_norm) {
    int e = blockIdx.x * blockDim.x + threadIdx.x;
    if (e >= E) return;
    int s = ei[e], d = ei[E + e];
    float nrm = dis[s] * ea[e] * dis[d];
    int pos = rowstart[d] + atomicAdd(&cursor[d], 1);
    csr_src[pos] = s;
    csr_norm[pos] = nrm;
}

// ---------------- small GEMM: C[M,NOUT] = A[M,64] @ W[NOUT,64]^T (+bias) ----------------
template <int NOUT>
__global__ __launch_bounds__(256) void gemm_kernel(const float* __restrict__ A,
                                                   const float* __restrict__ W,
                                                   const float* __restrict__ bias,
                                                   float* __restrict__ C) {
    __shared__ float Ws[NOUT * 65];   // padded stride 65: conflict-free reads
    __shared__ float As[16 * 64];
    int row0 = blockIdx.x * 16;
    for (int idx = threadIdx.x; idx < NOUT * 64; idx += 256) {
        int c = idx >> 6, k = idx & 63;
        Ws[c * 65 + k] = W[idx];
    }
    for (int idx = threadIdx.x; idx < 16 * 64; idx += 256)
        As[idx] = A[(size_t)row0 * 64 + idx];
    __syncthreads();
    for (int idx = threadIdx.x; idx < 16 * NOUT; idx += 256) {
        int r = idx / NOUT, c = idx - r * NOUT;
        float acc = bias ? bias[c] : 0.0f;
#pragma unroll
        for (int k = 0; k < 64; ++k) acc += As[r * 64 + k] * Ws[c * 65 + k];
        C[(size_t)(row0 + r) * NOUT + c] = acc;
    }
}

// ---------------- GCN aggregation via CSR gather (no atomics) ----------------
// FD=64, fused +bias, ReLU. One wave per node, lane = feature.
__global__ __launch_bounds__(256) void agg_relu64_kernel(const int* __restrict__ rowstart,
        const int* __restrict__ csr_src, const float* __restrict__ csr_norm,
        const float* __restrict__ dis, const float* __restrict__ H,
        const float* __restrict__ bias, float* __restrict__ out) {
    int node = (blockIdx.x * blockDim.x + threadIdx.x) >> 6;
    int lane = threadIdx.x & 63;
    if (node >= N) return;
    float di = dis[node];
    float acc = di * di * H[(size_t)node * 64 + lane];  // self-loop, weight 1
    int jb = rowstart[node], je = rowstart[node + 1];
    int j = jb;
    for (; j + 1 < je; j += 2) {
        int   s0 = csr_src[j],     s1 = csr_src[j + 1];
        float n0 = csr_norm[j],    n1 = csr_norm[j + 1];
        acc += n0 * H[(size_t)s0 * 64 + lane];
        acc += n1 * H[(size_t)s1 * 64 + lane];
    }
    if (j < je) acc += csr_norm[j] * H[(size_t)csr_src[j] * 64 + lane];
    out[(size_t)node * 64 + lane] = fmaxf(acc + bias[lane], 0.0f);
}

// FD=86: 128 threads per node (f < 86 active).
__global__ __launch_bounds__(256) void agg86_kernel(const int* __restrict__ rowstart,
        const int* __restrict__ csr_src, const float* __restrict__ csr_norm,
        const float* __restrict__ dis, const float* __restrict__ H,
        float* __restrict__ out) {
    int g = blockIdx.x * blockDim.x + threadIdx.x;
    int node = g >> 7;
    int f = g & 127;
    if (node >= N || f >= OUTF) return;
    float di = dis[node];
    float acc = di * di * H[(size_t)node * OUTF + f];
    int jb = rowstart[node], je = rowstart[node + 1];
    int j = jb;
    for (; j + 1 < je; j += 2) {
        int   s0 = csr_src[j],     s1 = csr_src[j + 1];
        float n0 = csr_norm[j],    n1 = csr_norm[j + 1];
        acc += n0 * H[(size_t)s0 * OUTF + f];
        acc += n1 * H[(size_t)s1 * OUTF + f];
    }
    if (j < je) acc += csr_norm[j] * H[(size_t)csr_src[j] * OUTF + f];
    out[(size_t)node * OUTF + f] = acc;
}

// ---------------- flash attention (fp32, KV-split partials) ----------------
// grid (N/256, HEADS, NSPLIT); block 256 = one query per thread, one K-tile of 256.
__global__ __launch_bounds__(256, 4) void attn_kernel(const float* __restrict__ qkv,
                                                      float* __restrict__ o_part,
                                                      float* __restrict__ m_part,
                                                      float* __restrict__ l_part) {
    int qi = blockIdx.x * 256 + threadIdx.x;
    int h  = blockIdx.y;
    int sp = blockIdx.z;
    // transposed float4 planes: writes conflict-free (consecutive lanes -> consecutive 16B),
    // reads wave-broadcast (all lanes same addr)
    __shared__ float4 Ks[4][KT];
    __shared__ float4 Vs[4][KT];

    {
        int key = sp * KT + threadIdx.x;
        const float* kp = qkv + (size_t)key * 192 + 64 + h * DH;
        const float* vp = kp + 64;
#pragma unroll
        for (int d4 = 0; d4 < 4; ++d4) {
            Ks[d4][threadIdx.x] = *(const float4*)(kp + d4 * 4);
            Vs[d4][threadIdx.x] = *(const float4*)(vp + d4 * 4);
        }
    }

    float4 q[4];
    {
        const float* qp = qkv + (size_t)qi * 192 + h * DH;
#pragma unroll
        for (int d4 = 0; d4 < 4; ++d4) {
            float4 t = *(const float4*)(qp + d4 * 4);
            q[d4] = make_float4(t.x * 0.25f, t.y * 0.25f, t.z * 0.25f, t.w * 0.25f);
        }
    }
    float4 o0 = {0, 0, 0, 0}, o1 = {0, 0, 0, 0}, o2 = {0, 0, 0, 0}, o3 = {0, 0, 0, 0};
    float m = -1e30f, l = 0.0f;
    __syncthreads();

#pragma unroll 2
    for (int j = 0; j < KT; ++j) {
        float4 k0 = Ks[0][j], k1 = Ks[1][j], k2 = Ks[2][j], k3 = Ks[3][j];
        float s = k0.x * q[0].x + k0.y * q[0].y + k0.z * q[0].z + k0.w * q[0].w
                + k1.x * q[1].x + k1.y * q[1].y + k1.z * q[1].z + k1.w * q[1].w
                + k2.x * q[2].x + k2.y * q[2].y + k2.z * q[2].z + k2.w * q[2].w
                + k3.x * q[3].x + k3.y * q[3].y + k3.z * q[3].z + k3.w * q[3].w;
        float4 v0 = Vs[0][j], v1 = Vs[1][j], v2 = Vs[2][j], v3 = Vs[3][j];
        if (s <= m) {                       // common path: max unchanged
            float p = __expf(s - m);
            l += p;
            o0.x += p * v0.x; o0.y += p * v0.y; o0.z += p * v0.z; o0.w += p * v0.w;
            o1.x += p * v1.x; o1.y += p * v1.y; o1.z += p * v1.z; o1.w += p * v1.w;
            o2.x += p * v2.x; o2.y += p * v2.y; o2.z += p * v2.z; o2.w += p * v2.w;
            o3.x += p * v3.x; o3.y += p * v3.y; o3.z += p * v3.z; o3.w += p * v3.w;
        } else {                            // rare: new max, rescale
            float c = __expf(m - s);
            m = s;
            l = l * c + 1.0f;
            o0.x = o0.x * c + v0.x; o0.y = o0.y * c + v0.y; o0.z = o0.z * c + v0.z; o0.w = o0.w * c + v0.w;
            o1.x = o1.x * c + v1.x; o1.y = o1.y * c + v1.y; o1.z = o1.z * c + v1.z; o1.w = o1.w * c + v1.w;
            o2.x = o2.x * c + v2.x; o2.y = o2.y * c + v2.y; o2.z = o2.z * c + v2.z; o2.w = o2.w * c + v2.w;
            o3.x = o3.x * c + v3.x; o3.y = o3.y * c + v3.y; o3.z = o3.z * c + v3.z; o3.w = o3.w * c + v3.w;
        }
    }
    size_t pidx = ((size_t)h * N + qi) * NSPLIT + sp;
    m_part[pidx] = m;
    l_part[pidx] = l;
    float* op = o_part + pidx * DH;
    *(float4*)(op + 0)  = o0;
    *(float4*)(op + 4)  = o1;
    *(float4*)(op + 8)  = o2;
    *(float4*)(op + 12) = o3;
}

__global__ void combine_kernel(const float* __restrict__ o_part, const float* __restrict__ m_part,
                               const float* __restrict__ l_part, float* __restrict__ o) {
    int t = blockIdx.x * blockDim.x + threadIdx.x;
    if (t >= HEADS * N) return;
    int h = t / N, qi = t - h * N;
    size_t base = ((size_t)h * N + qi) * NSPLIT;
    float M = -1e30f;
#pragma unroll
    for (int s = 0; s < NSPLIT; ++s) M = fmaxf(M, m_part[base + s]);
    float L = 0.0f;
    float acc[DH];
#pragma unroll
    for (int d = 0; d < DH; ++d) acc[d] = 0.0f;
    for (int s = 0; s < NSPLIT; ++s) {
        float c = __expf(m_part[base + s] - M);
        L += c * l_part[base + s];
        const float* op = o_part + (base + s) * DH;
#pragma unroll
        for (int d = 0; d < DH; ++d) acc[d] += c * op[d];
    }
    float inv = 1.0f / L;
#pragma unroll
    for (int d = 0; d < DH; ++d) o[(size_t)qi * 64 + h * DH + d] = acc[d] * inv;
}

// ---------------- pooled mean per graph (batch sorted) ----------------
__global__ void pool_kernel(const float* __restrict__ h2, const int* __restrict__ batch,
                            const float* __restrict__ b2, float* __restrict__ out) {
    int b = blockIdx.x;
    int lo = 0, hi = N;
    while (lo < hi) { int mid = (lo + hi) >> 1; if (batch[mid] < b) lo = mid + 1; else hi = mid; }
    int start = lo;
    lo = start; hi = N;
    while (lo < hi) { int mid = (lo + hi) >> 1; if (batch[mid] < b + 1) lo = mid + 1; else hi = mid; }
    int end = lo;
    int f = threadIdx.x;
    if (f >= OUTF) return;
    float acc = 0.0f;
    for (int i = start; i < end; ++i) acc += h2[(size_t)i * OUTF + f];
    if (end > start)
        out[b * OUTF + f] = acc / (float)(end - start) + b2[f];
    else
        out[b * OUTF + f] = 0.0f;
}

extern "C" void kernel_launch(void* const* d_in, const int* in_sizes, int n_in,
                              void* d_out, int out_size, void* d_ws, size_t ws_size,
                              hipStream_t stream) {
    const float* x     = (const float*)d_in[0];
    const int*   ei    = (const int*)  d_in[1];
    const float* ea    = (const float*)d_in[2];
    const int*   batch = (const int*)  d_in[3];
    const float* W1    = (const float*)d_in[4];
    const float* b1    = (const float*)d_in[5];
    const float* Win   = (const float*)d_in[6];
    const float* b_in  = (const float*)d_in[7];
    const float* Wout  = (const float*)d_in[8];
    const float* b_out = (const float*)d_in[9];
    const float* W2    = (const float*)d_in[10];
    const float* b2    = (const float*)d_in[11];
    float* out = (float*)d_out;
    float* ws  = (float*)d_ws;

    float* deg      = ws + OFF_DEG;
    int*   counts   = (int*)(ws + OFF_CNT);
    int*   cursor   = (int*)(ws + OFF_CUR);
    float* dis      = ws + OFF_DIS;
    int*   rowstart = (int*)(ws + OFF_ROW);
    int*   csr_src  = (int*)(ws + OFF_CSRC);
    float* csr_norm = ws + OFF_CNRM;
    float* bufA     = ws + OFF_BUFA;
    float* bufB     = ws + OFF_BUFB;
    float* qkv      = ws + OFF_QKV;
    float* opart    = ws + OFF_OPART;
    float* mpart    = ws + OFF_MPART;
    float* lpart    = ws + OFF_LPART;
    float* h2agg    = ws + OFF_H2AGG;

    // CSR build: deg/counts/cursor zeroed in one memset (contiguous)
    hipMemsetAsync(deg, 0, (size_t)3 * N * 4, stream);
    hist_kernel<<<(E + 255) / 256, 256, 0, stream>>>(ei, ea, deg, counts);
    scan_dis_kernel<<<1, 1024, 0, stream>>>(counts, deg, rowstart, dis);
    fill_kernel<<<(E + 255) / 256, 256, 0, stream>>>(ei, ea, dis, rowstart, cursor,
                                                     csr_src, csr_norm);

    // GCN1: xW1 -> gather-aggregate (+b1, ReLU fused)
    gemm_kernel<64><<<N / 16, 256, 0, stream>>>(x, W1, nullptr, bufA);
    agg_relu64_kernel<<<(N * 64) / 256, 256, 0, stream>>>(rowstart, csr_src, csr_norm, dis,
                                                          bufA, b1, bufB);

    // QKV projection
    gemm_kernel<192><<<N / 16, 256, 0, stream>>>(bufB, Win, b_in, qkv);

    // flash attention with KV splits, combine into bufB (=o, [N,64])
    attn_kernel<<<dim3(N / 256, HEADS, NSPLIT), 256, 0, stream>>>(qkv, opart, mpart, lpart);
    combine_kernel<<<(HEADS * N + 255) / 256, 256, 0, stream>>>(opart, mpart, lpart, bufB);

    // output projection: bufA = o @ Wout^T + b_out
    gemm_kernel<64><<<N / 16, 256, 0, stream>>>(bufB, Wout, b_out, bufA);

    // GCN2: h2pre = bufA @ W2^T (into qkv buffer), gather-aggregate (bias folded into pool)
    gemm_kernel<86><<<N / 16, 256, 0, stream>>>(bufA, W2, nullptr, qkv);
    agg86_kernel<<<(N * 128) / 256, 256, 0, stream>>>(rowstart, csr_src, csr_norm, dis,
                                                      qkv, h2agg);

    // pooled mean + b2
    pool_kernel<<<NB, 128, 0, stream>>>(h2agg, batch, b2, out);
}

// Round 3
// 224.165 us; speedup vs baseline: 1.8435x; 1.5077x over previous
//
#include <hip/hip_runtime.h>

// Problem constants
constexpr int N = 4096, E = 131072, F = 64, HID = 64, OUTF = 86, NB = 16, HEADS = 4, DH = 16;
constexpr int NSPLIT = 8;   // KV splits for flash attention
constexpr int PC = 8;       // pool partial chunks per graph

typedef __attribute__((ext_vector_type(8))) short short8;
typedef __attribute__((ext_vector_type(4))) float f32x4;

// Workspace layout (offsets in float units; all 16B-aligned)
constexpr size_t OFF_DEG   = 0;                    // N floats
constexpr size_t OFF_CNT   = OFF_DEG + N;          // N ints (counts)
constexpr size_t OFF_CUR   = OFF_CNT + N;          // N ints (fill cursors)
constexpr size_t OFF_DIS   = OFF_CUR + N;          // N floats
constexpr size_t OFF_ROW   = OFF_DIS + N;          // N+16 ints (rowstart)
constexpr size_t OFF_CSRC  = OFF_ROW + N + 16;     // E ints  (csr src)
constexpr size_t OFF_CNRM  = OFF_CSRC + E;         // E floats (csr norm)
constexpr size_t OFF_BUFA  = OFF_CNRM + E;         // N*64: xW1, later o@Wout
constexpr size_t OFF_BUFB  = OFF_BUFA + (size_t)N * 64;   // N*64: h1, later o
constexpr size_t OFF_QKV   = OFF_BUFB + (size_t)N * 64;   // N*192: qkv, later h2pre (N*86)
constexpr size_t OFF_OPART = OFF_QKV + (size_t)N * 192;   // HEADS*N*NSPLIT*DH
constexpr size_t OFF_LPART = OFF_OPART + (size_t)HEADS * N * NSPLIT * DH;  // HEADS*N*NSPLIT
constexpr size_t OFF_PBUF  = OFF_LPART + (size_t)HEADS * N * NSPLIT;       // NB*PC*OUTF
constexpr size_t OFF_PCNT  = OFF_PBUF + (size_t)NB * PC * OUTF;            // NB*PC ints
constexpr size_t OFF_H2AGG = OFF_OPART;            // reuse after combine (N*86)

__device__ inline unsigned short f2bf(float f) {  // RNE float->bf16
    unsigned u = __builtin_bit_cast(unsigned, f);
    u += 0x7FFFu + ((u >> 16) & 1u);
    return (unsigned short)(u >> 16);
}

// ---------------- CSR build: histogram (+weighted degree) ----------------
__global__ void hist_kernel(const int* __restrict__ ei, const float* __restrict__ ea,
                            float* __restrict__ deg, int* __restrict__ counts) {
    int i = blockIdx.x * blockDim.x + threadIdx.x;
    if (i < E) {
        int d = ei[E + i];
        atomicAdd(&deg[d], ea[i]);
        atomicAdd(&counts[d], 1);
    }
}

// single block, 1024 threads: exclusive scan of counts -> rowstart; dis = rsqrt(deg+1)
__global__ __launch_bounds__(1024) void scan_dis_kernel(const int* __restrict__ counts,
                                                        const float* __restrict__ deg,
                                                        int* __restrict__ rowstart,
                                                        float* __restrict__ dis) {
    __shared__ int sums[1024];
    int t = threadIdx.x;
    int c[4];
    int base = t * 4;
    int s = 0;
#pragma unroll
    for (int k = 0; k < 4; ++k) { c[k] = counts[base + k]; s += c[k]; }
    sums[t] = s;
    __syncthreads();
    for (int off = 1; off < 1024; off <<= 1) {
        int v = (t >= off) ? sums[t - off] : 0;
        __syncthreads();
        sums[t] += v;
        __syncthreads();
    }
    int run = (t > 0) ? sums[t - 1] : 0;
#pragma unroll
    for (int k = 0; k < 4; ++k) { rowstart[base + k] = run; run += c[k]; }
    if (t == 1023) rowstart[N] = run;
    for (int i = t; i < N; i += 1024) dis[i] = rsqrtf(deg[i] + 1.0f);  // +1 self-loop; > 0
}

__global__ void fill_kernel(const int* __restrict__ ei, const float* __restrict__ ea,
                            const float* __restrict__ dis, const int* __restrict__ rowstart,
                            int* __restrict__ cursor, int* __restrict__ csr_src,
                            float* __restrict__ csr_norm) {
    int e = blockIdx.x * blockDim.x + threadIdx.x;
    if (e >= E) return;
    int s = ei[e], d = ei[E + e];
    float nrm = dis[s] * ea[e] * dis[d];
    int pos = rowstart[d] + atomicAdd(&cursor[d], 1);
    csr_src[pos] = s;
    csr_norm[pos] = nrm;
}

// ---------------- small GEMM: C[M,NOUT] = A[M,64] @ W[NOUT,64]^T (+bias) ----------------
template <int NOUT>
__global__ __launch_bounds__(256) void gemm_kernel(const float* __restrict__ A,
                                                   const float* __restrict__ W,
                                                   const float* __restrict__ bias,
                                                   float* __restrict__ C) {
    __shared__ float Ws[NOUT * 65];
    __shared__ float As[16 * 64];
    int row0 = blockIdx.x * 16;
    for (int idx = threadIdx.x; idx < NOUT * 64; idx += 256) {
        int c = idx >> 6, k = idx & 63;
        Ws[c * 65 + k] = W[idx];
    }
    for (int idx = threadIdx.x; idx < 16 * 64; idx += 256)
        As[idx] = A[(size_t)row0 * 64 + idx];
    __syncthreads();
    for (int idx = threadIdx.x; idx < 16 * NOUT; idx += 256) {
        int r = idx / NOUT, c = idx - r * NOUT;
        float acc = bias ? bias[c] : 0.0f;
#pragma unroll
        for (int k = 0; k < 64; ++k) acc += As[r * 64 + k] * Ws[c * 65 + k];
        C[(size_t)(row0 + r) * NOUT + c] = acc;
    }
}

// ---------------- GCN aggregation via CSR gather ----------------
__global__ __launch_bounds__(256) void agg_relu64_kernel(const int* __restrict__ rowstart,
        const int* __restrict__ csr_src, const float* __restrict__ csr_norm,
        const float* __restrict__ dis, const float* __restrict__ H,
        const float* __restrict__ bias, float* __restrict__ out) {
    int node = (blockIdx.x * blockDim.x + threadIdx.x) >> 6;
    int lane = threadIdx.x & 63;
    if (node >= N) return;
    float di = dis[node];
    float acc = di * di * H[(size_t)node * 64 + lane];
    int jb = rowstart[node], je = rowstart[node + 1];
    int j = jb;
    for (; j + 1 < je; j += 2) {
        int   s0 = csr_src[j],  s1 = csr_src[j + 1];
        float n0 = csr_norm[j], n1 = csr_norm[j + 1];
        acc += n0 * H[(size_t)s0 * 64 + lane];
        acc += n1 * H[(size_t)s1 * 64 + lane];
    }
    if (j < je) acc += csr_norm[j] * H[(size_t)csr_src[j] * 64 + lane];
    out[(size_t)node * 64 + lane] = fmaxf(acc + bias[lane], 0.0f);
}

__global__ __launch_bounds__(256) void agg86_kernel(const int* __restrict__ rowstart,
        const int* __restrict__ csr_src, const float* __restrict__ csr_norm,
        const float* __restrict__ dis, const float* __restrict__ H,
        float* __restrict__ out) {
    int g = blockIdx.x * blockDim.x + threadIdx.x;
    int node = g >> 7;
    int f = g & 127;
    if (node >= N || f >= OUTF) return;
    float di = dis[node];
    float acc = di * di * H[(size_t)node * OUTF + f];
    int jb = rowstart[node], je = rowstart[node + 1];
    int j = jb;
    for (; j + 1 < je; j += 2) {
        int   s0 = csr_src[j],  s1 = csr_src[j + 1];
        float n0 = csr_norm[j], n1 = csr_norm[j + 1];
        acc += n0 * H[(size_t)s0 * OUTF + f];
        acc += n1 * H[(size_t)s1 * OUTF + f];
    }
    if (j < je) acc += csr_norm[j] * H[(size_t)csr_src[j] * OUTF + f];
    out[(size_t)node * OUTF + f] = acc;
}

// ---------------- MFMA flash attention (bf16, no-max softmax: scores are tiny) ----------------
// grid (N/64, HEADS, NSPLIT); 256 threads = 4 waves; wave = 16 queries x 512 keys.
// S^T = K.Q^T so P exits in A-layout query index (lane&15); LDS roundtrip for key index.
__global__ __launch_bounds__(256) void attn_mfma_kernel(const float* __restrict__ qkv,
        float* __restrict__ o_part, float* __restrict__ l_part) {
    constexpr int KEYS = N / NSPLIT;       // 512
    constexpr int KROW = 24;               // shorts per K row (48 B: 16 bf16 + pad, bank-spread)
    constexpr int VROW = KEYS + 8;         // shorts per V^T row (pad keeps 16B align + bank spread)
    __shared__ __align__(16) unsigned short Klds[KEYS * KROW];   // [key][dh] bf16
    __shared__ __align__(16) unsigned short VTlds[16 * VROW];    // [dh][key] bf16
    __shared__ __align__(16) unsigned short Plds[4 * 16 * 40];   // per-wave [query][key0..31] pad 40

    const int h  = blockIdx.y;
    const int sp = blockIdx.z;
    const int k0 = sp * KEYS;
    const int tid = threadIdx.x;
    const int lane = tid & 63, wv = tid >> 6;
    const int q15 = lane & 15, quad = lane >> 4;

    // stage K,V (bf16) for this head+split
    for (int key = tid; key < KEYS; key += 256) {
        const float* kp = qkv + (size_t)(k0 + key) * 192 + 64 + h * 16;
        unsigned short kb[16];
#pragma unroll
        for (int d = 0; d < 16; ++d) kb[d] = f2bf(kp[d]);
        *(short8*)&Klds[key * KROW]     = *(const short8*)&kb[0];
        *(short8*)&Klds[key * KROW + 8] = *(const short8*)&kb[8];
        const float* vp = kp + 64;
#pragma unroll
        for (int d = 0; d < 16; ++d) VTlds[d * VROW + key] = f2bf(vp[d]);
    }

    // Q fragment (B-operand): n=query=lane&15, k=dh=quad*8+j (quad<2 real, rest zero-pad)
    const int qbase = blockIdx.x * 64 + wv * 16;
    short8 qf = {};
    if (quad < 2) {
        const float* qp = qkv + (size_t)(qbase + q15) * 192 + h * 16 + quad * 8;
        unsigned short qb[8];
#pragma unroll
        for (int d = 0; d < 8; ++d) qb[d] = f2bf(qp[d] * 0.25f);  // 1/sqrt(DH) folded in
        qf = *(const short8*)&qb[0];
    }
    f32x4 O = {0.f, 0.f, 0.f, 0.f};
    float l = 0.f;
    unsigned short* Pw = &Plds[wv * 640];
    __syncthreads();

    for (int ch = 0; ch < KEYS / 32; ++ch) {
#pragma unroll
        for (int t = 0; t < 2; ++t) {
            // K fragment (A-operand): m=key=lane&15, k=dh=quad*8+j
            short8 kf = {};
            if (quad < 2)
                kf = *(const short8*)&Klds[(ch * 32 + t * 16 + q15) * KROW + quad * 8];
            f32x4 zero = {0.f, 0.f, 0.f, 0.f};
            f32x4 s = __builtin_amdgcn_mfma_f32_16x16x32_bf16(kf, qf, zero, 0, 0, 0);
            // C-layout: col=query=lane&15, row=key=quad*4+reg
            float p0 = __expf(s[0]), p1 = __expf(s[1]), p2 = __expf(s[2]), p3 = __expf(s[3]);
            l += p0 + p1 + p2 + p3;
            ushort4 pu;
            pu.x = f2bf(p0); pu.y = f2bf(p1); pu.z = f2bf(p2); pu.w = f2bf(p3);
            *(ushort4*)&Pw[q15 * 40 + t * 16 + quad * 4] = pu;   // P[query][key]
        }
        asm volatile("s_waitcnt lgkmcnt(0)" ::: "memory");
        // P fragment (A): m=query=lane&15, k=key=quad*8+j
        short8 pf = *(const short8*)&Pw[q15 * 40 + quad * 8];
        // V fragment (B): n=dh=lane&15, k=key=quad*8+j
        short8 vf = *(const short8*)&VTlds[q15 * VROW + ch * 32 + quad * 8];
        O = __builtin_amdgcn_mfma_f32_16x16x32_bf16(pf, vf, O, 0, 0, 0);
    }

    // epilogue: l lives at query=lane&15; sum the 4 quad partials
    l += __shfl_xor(l, 16);
    l += __shfl_xor(l, 32);
    if (lane < 16)
        l_part[((size_t)h * N + qbase + q15) * NSPLIT + sp] = l;
    // O C-layout: row=query=quad*4+r, col=dh=lane&15
#pragma unroll
    for (int r = 0; r < 4; ++r) {
        int query = qbase + quad * 4 + r;
        o_part[(((size_t)h * N + query) * NSPLIT + sp) * 16 + q15] = O[r];
    }
}

__global__ void combine_kernel(const float4* __restrict__ o_part, const float* __restrict__ l_part,
                               float* __restrict__ o) {
    int t = blockIdx.x * blockDim.x + threadIdx.x;
    if (t >= HEADS * N) return;
    int h = t / N, qi = t - h * N;
    float4 acc[4] = {};
    const float4* op = o_part + (size_t)t * NSPLIT * 4;
    for (int s = 0; s < NSPLIT; ++s) {
#pragma unroll
        for (int d = 0; d < 4; ++d) {
            float4 v = op[s * 4 + d];
            acc[d].x += v.x; acc[d].y += v.y; acc[d].z += v.z; acc[d].w += v.w;
        }
    }
    float L = 0.f;
    const float* lp = l_part + (size_t)t * NSPLIT;
#pragma unroll
    for (int s = 0; s < NSPLIT; ++s) L += lp[s];
    float inv = 1.0f / L;
    float4* od = (float4*)(o + (size_t)qi * 64 + h * 16);
#pragma unroll
    for (int d = 0; d < 4; ++d)
        od[d] = make_float4(acc[d].x * inv, acc[d].y * inv, acc[d].z * inv, acc[d].w * inv);
}

// ---------------- pooled mean per graph (two-phase) ----------------
__global__ void pool_partial_kernel(const float* __restrict__ h2, const int* __restrict__ batch,
                                    float* __restrict__ pbuf, int* __restrict__ pcnt) {
    int b = blockIdx.x, c = blockIdx.y;
    int lo = 0, hi = N;
    while (lo < hi) { int mid = (lo + hi) >> 1; if (batch[mid] < b) lo = mid + 1; else hi = mid; }
    int start = lo;
    lo = start; hi = N;
    while (lo < hi) { int mid = (lo + hi) >> 1; if (batch[mid] < b + 1) lo = mid + 1; else hi = mid; }
    int end = lo;
    int len = end - start;
    int cs = start + (int)((long long)len * c / PC);
    int ce = start + (int)((long long)len * (c + 1) / PC);
    int f = threadIdx.x;
    if (f == 0) pcnt[b * PC + c] = ce - cs;
    if (f >= OUTF) return;
    float acc = 0.f;
    for (int i = cs; i < ce; ++i) acc += h2[(size_t)i * OUTF + f];
    pbuf[(b * PC + c) * OUTF + f] = acc;
}

__global__ void pool_final_kernel(const float* __restrict__ pbuf, const int* __restrict__ pcnt,
                                  const float* __restrict__ b2, float* __restrict__ out) {
    int b = blockIdx.x, f = threadIdx.x;
    if (f >= OUTF) return;
    float acc = 0.f;
    int cnt = 0;
#pragma unroll
    for (int c = 0; c < PC; ++c) {
        acc += pbuf[(b * PC + c) * OUTF + f];
        cnt += pcnt[b * PC + c];
    }
    out[b * OUTF + f] = cnt > 0 ? acc / (float)cnt + b2[f] : 0.0f;
}

extern "C" void kernel_launch(void* const* d_in, const int* in_sizes, int n_in,
                              void* d_out, int out_size, void* d_ws, size_t ws_size,
                              hipStream_t stream) {
    const float* x     = (const float*)d_in[0];
    const int*   ei    = (const int*)  d_in[1];
    const float* ea    = (const float*)d_in[2];
    const int*   batch = (const int*)  d_in[3];
    const float* W1    = (const float*)d_in[4];
    const float* b1    = (const float*)d_in[5];
    const float* Win   = (const float*)d_in[6];
    const float* b_in  = (const float*)d_in[7];
    const float* Wout  = (const float*)d_in[8];
    const float* b_out = (const float*)d_in[9];
    const float* W2    = (const float*)d_in[10];
    const float* b2    = (const float*)d_in[11];
    float* out = (float*)d_out;
    float* ws  = (float*)d_ws;

    float* deg      = ws + OFF_DEG;
    int*   counts   = (int*)(ws + OFF_CNT);
    int*   cursor   = (int*)(ws + OFF_CUR);
    float* dis      = ws + OFF_DIS;
    int*   rowstart = (int*)(ws + OFF_ROW);
    int*   csr_src  = (int*)(ws + OFF_CSRC);
    float* csr_norm = ws + OFF_CNRM;
    float* bufA     = ws + OFF_BUFA;
    float* bufB     = ws + OFF_BUFB;
    float* qkv      = ws + OFF_QKV;
    float* opart    = ws + OFF_OPART;
    float* lpart    = ws + OFF_LPART;
    float* pbuf     = ws + OFF_PBUF;
    int*   pcnt     = (int*)(ws + OFF_PCNT);
    float* h2agg    = ws + OFF_H2AGG;

    // CSR build: deg/counts/cursor zeroed in one memset (contiguous)
    hipMemsetAsync(deg, 0, (size_t)3 * N * 4, stream);
    hist_kernel<<<(E + 255) / 256, 256, 0, stream>>>(ei, ea, deg, counts);
    scan_dis_kernel<<<1, 1024, 0, stream>>>(counts, deg, rowstart, dis);
    fill_kernel<<<(E + 255) / 256, 256, 0, stream>>>(ei, ea, dis, rowstart, cursor,
                                                     csr_src, csr_norm);

    // GCN1: xW1 -> gather-aggregate (+b1, ReLU fused)
    gemm_kernel<64><<<N / 16, 256, 0, stream>>>(x, W1, nullptr, bufA);
    agg_relu64_kernel<<<(N * 64) / 256, 256, 0, stream>>>(rowstart, csr_src, csr_norm, dis,
                                                          bufA, b1, bufB);

    // QKV projection
    gemm_kernel<192><<<N / 16, 256, 0, stream>>>(bufB, Win, b_in, qkv);

    // MFMA flash attention + combine into bufB (=o, [N,64])
    attn_mfma_kernel<<<dim3(N / 64, HEADS, NSPLIT), 256, 0, stream>>>(qkv, opart, lpart);
    combine_kernel<<<(HEADS * N + 255) / 256, 256, 0, stream>>>((const float4*)opart, lpart, bufB);

    // output projection: bufA = o @ Wout^T + b_out
    gemm_kernel<64><<<N / 16, 256, 0, stream>>>(bufB, Wout, b_out, bufA);

    // GCN2: h2pre = bufA @ W2^T (into qkv buffer), gather-aggregate (bias folded into pool)
    gemm_kernel<86><<<N / 16, 256, 0, stream>>>(bufA, W2, nullptr, qkv);
    agg86_kernel<<<(N * 128) / 256, 256, 0, stream>>>(rowstart, csr_src, csr_norm, dis,
                                                      qkv, h2agg);

    // pooled mean + b2 (two-phase)
    pool_partial_kernel<<<dim3(NB, PC), 128, 0, stream>>>(h2agg, batch, pbuf, pcnt);
    pool_final_kernel<<<NB, 128, 0, stream>>>(pbuf, pcnt, b2, out);
}

// Round 4
// 215.446 us; speedup vs baseline: 1.9181x; 1.0405x over previous
//
#include <hip/hip_runtime.h>

// Problem constants
constexpr int N = 4096, E = 131072, F = 64, HID = 64, OUTF = 86, NB = 16, HEADS = 4, DH = 16;
constexpr int NSPLIT = 8;   // KV splits for flash attention
constexpr int KEYS = N / NSPLIT;  // 512
constexpr int PC = 8;       // pool partial chunks per graph

typedef __attribute__((ext_vector_type(8))) short short8;
typedef __attribute__((ext_vector_type(4))) float f32x4;

// Workspace layout (float units; all 16B-aligned)
constexpr size_t OFF_DEG   = 0;                      // N floats
constexpr size_t OFF_CNT   = OFF_DEG + N;            // N ints
constexpr size_t OFF_CUR   = OFF_CNT + N;            // N ints
constexpr size_t OFF_DIS   = OFF_CUR + N;            // N floats
constexpr size_t OFF_ROW   = OFF_DIS + N;            // N+16 ints
constexpr size_t OFF_CSRC  = OFF_ROW + N + 16;       // E ints
constexpr size_t OFF_CNRM  = OFF_CSRC + E;           // E floats
constexpr size_t OFF_BUFA  = OFF_CNRM + E;                 // N*64
constexpr size_t OFF_BUFB  = OFF_BUFA + (size_t)N * 64;    // N*64
constexpr size_t OFF_QP    = OFF_BUFB + (size_t)N * 64;    // HEADS*N*16 bf16 = N*32 floats
constexpr size_t OFF_KP    = OFF_QP + (size_t)N * 32;
constexpr size_t OFF_VP    = OFF_KP + (size_t)N * 32;      // [h][16][N] bf16
constexpr size_t OFF_H2PRE = OFF_VP + (size_t)N * 32;      // N*86
constexpr size_t OFF_H2AGG = OFF_H2PRE + (size_t)N * 86;   // N*86
constexpr size_t OFF_OPART = OFF_H2AGG + (size_t)N * 86;   // HEADS*N*NSPLIT*16
constexpr size_t OFF_LPART = OFF_OPART + (size_t)HEADS * N * NSPLIT * 16;
constexpr size_t OFF_PBUF  = OFF_LPART + (size_t)HEADS * N * NSPLIT;
constexpr size_t OFF_PCNT  = OFF_PBUF + (size_t)NB * PC * OUTF;

__device__ inline unsigned short f2bf(float f) {  // RNE float->bf16
    unsigned u = __builtin_bit_cast(unsigned, f);
    u += 0x7FFFu + ((u >> 16) & 1u);
    return (unsigned short)(u >> 16);
}

// ---------------- CSR build ----------------
__global__ void hist_kernel(const int* __restrict__ ei, const float* __restrict__ ea,
                            float* __restrict__ deg, int* __restrict__ counts) {
    int i = blockIdx.x * blockDim.x + threadIdx.x;
    if (i < E) {
        int d = ei[E + i];
        atomicAdd(&deg[d], ea[i]);
        atomicAdd(&counts[d], 1);
    }
}

// 1 block, 256 threads: shfl-based exclusive scan (16 counts/thread), dis = rsqrt(deg+1)
__global__ __launch_bounds__(256) void scan_dis_kernel(const int* __restrict__ counts,
                                                       const float* __restrict__ deg,
                                                       int* __restrict__ rowstart,
                                                       float* __restrict__ dis) {
    __shared__ int wtot[4];
    int t = threadIdx.x, lane = t & 63, wv = t >> 6;
    int c[16], s = 0;
#pragma unroll
    for (int k = 0; k < 16; ++k) { c[k] = counts[t * 16 + k]; s += c[k]; }
    int inc = s;
#pragma unroll
    for (int off = 1; off < 64; off <<= 1) {
        int v = __shfl_up(inc, off);
        if (lane >= off) inc += v;
    }
    if (lane == 63) wtot[wv] = inc;
    __syncthreads();
    int woff = 0;
#pragma unroll
    for (int w = 0; w < 4; ++w) woff += (w < wv) ? wtot[w] : 0;
    int start = woff + inc - s;  // exclusive prefix
#pragma unroll
    for (int k = 0; k < 16; ++k) { rowstart[t * 16 + k] = start; start += c[k]; }
    if (t == 255) rowstart[N] = start;
    for (int i = t; i < N; i += 256) dis[i] = rsqrtf(deg[i] + 1.0f);  // +1 self-loop; > 0
}

__global__ void fill_kernel(const int* __restrict__ ei, const float* __restrict__ ea,
                            const float* __restrict__ dis, const int* __restrict__ rowstart,
                            int* __restrict__ cursor, int* __restrict__ csr_src,
                            float* __restrict__ csr_norm) {
    int e = blockIdx.x * blockDim.x + threadIdx.x;
    if (e >= E) return;
    int s = ei[e], d = ei[E + e];
    float nrm = dis[s] * ea[e] * dis[d];
    int pos = rowstart[d] + atomicAdd(&cursor[d], 1);
    csr_src[pos] = s;
    csr_norm[pos] = nrm;
}

// ---------------- GEMM: C[M,NOUT] = A[M,64] @ W[NOUT,64]^T (+bias) ----------------
// block = 16 rows; thread owns rows {r2, r2+8} x cols {cg+32i}; float4 LDS, pad stride 17.
template <int NOUT, int NOUTP, int IMAX>
__global__ __launch_bounds__(256) void gemm_kernel(const float* __restrict__ A,
                                                   const float* __restrict__ W,
                                                   const float* __restrict__ bias,
                                                   float* __restrict__ C) {
    __shared__ float4 Ws[NOUTP * 17];
    __shared__ float4 As[16 * 17];
    int row0 = blockIdx.x * 16;
    for (int idx = threadIdx.x; idx < NOUTP * 16; idx += 256) {
        int c = idx >> 4, k4 = idx & 15;
        float4 v = make_float4(0.f, 0.f, 0.f, 0.f);
        if (c < NOUT) v = ((const float4*)W)[idx];
        Ws[c * 17 + k4] = v;
    }
    {
        int r = threadIdx.x >> 4, k4 = threadIdx.x & 15;
        As[r * 17 + k4] = ((const float4*)A)[(size_t)(row0 + r) * 16 + k4];
    }
    __syncthreads();
    int r2 = threadIdx.x & 7, cg = threadIdx.x >> 3;
    float acc[2][IMAX];
#pragma unroll
    for (int j = 0; j < 2; ++j)
#pragma unroll
        for (int i = 0; i < IMAX; ++i) {
            int c = cg + 32 * i;
            acc[j][i] = (bias && c < NOUT) ? bias[c] : 0.0f;
        }
#pragma unroll
    for (int k4 = 0; k4 < 16; ++k4) {
        float4 a0 = As[r2 * 17 + k4];
        float4 a1 = As[(r2 + 8) * 17 + k4];
#pragma unroll
        for (int i = 0; i < IMAX; ++i) {
            float4 w = Ws[(cg + 32 * i) * 17 + k4];
            acc[0][i] += a0.x * w.x + a0.y * w.y + a0.z * w.z + a0.w * w.w;
            acc[1][i] += a1.x * w.x + a1.y * w.y + a1.z * w.z + a1.w * w.w;
        }
    }
#pragma unroll
    for (int j = 0; j < 2; ++j) {
        int row = row0 + r2 + 8 * j;
#pragma unroll
        for (int i = 0; i < IMAX; ++i) {
            int c = cg + 32 * i;
            if (c < NOUT) C[(size_t)row * NOUT + c] = acc[j][i];
        }
    }
}

// QKV GEMM (NOUT=192) with fused bf16 pack epilogue:
//   Qp[h][n][16] (pre-scaled 0.25), Kp[h][n][16], Vp[h][16][n]
__global__ __launch_bounds__(256) void gemm_qkv_kernel(const float* __restrict__ A,
        const float* __restrict__ W, const float* __restrict__ bias,
        unsigned short* __restrict__ Qp, unsigned short* __restrict__ Kp,
        unsigned short* __restrict__ Vp) {
    __shared__ float4 Ws[192 * 17];
    __shared__ float4 As[16 * 17];
    int row0 = blockIdx.x * 16;
    for (int idx = threadIdx.x; idx < 192 * 16; idx += 256) {
        int c = idx >> 4, k4 = idx & 15;
        Ws[c * 17 + k4] = ((const float4*)W)[idx];
    }
    {
        int r = threadIdx.x >> 4, k4 = threadIdx.x & 15;
        As[r * 17 + k4] = ((const float4*)A)[(size_t)(row0 + r) * 16 + k4];
    }
    __syncthreads();
    int r2 = threadIdx.x & 7, cg = threadIdx.x >> 3;
    float acc[2][6];
#pragma unroll
    for (int j = 0; j < 2; ++j)
#pragma unroll
        for (int i = 0; i < 6; ++i) acc[j][i] = bias[cg + 32 * i];
#pragma unroll
    for (int k4 = 0; k4 < 16; ++k4) {
        float4 a0 = As[r2 * 17 + k4];
        float4 a1 = As[(r2 + 8) * 17 + k4];
#pragma unroll
        for (int i = 0; i < 6; ++i) {
            float4 w = Ws[(cg + 32 * i) * 17 + k4];
            acc[0][i] += a0.x * w.x + a0.y * w.y + a0.z * w.z + a0.w * w.w;
            acc[1][i] += a1.x * w.x + a1.y * w.y + a1.z * w.z + a1.w * w.w;
        }
    }
#pragma unroll
    for (int j = 0; j < 2; ++j) {
        int row = row0 + r2 + 8 * j;
#pragma unroll
        for (int i = 0; i < 6; ++i) {
            int c = cg + 32 * i;
            float v = acc[j][i];
            if (c < 64) {
                int h = c >> 4, d = c & 15;
                Qp[((size_t)h * N + row) * 16 + d] = f2bf(v * 0.25f);  // 1/sqrt(DH)
            } else if (c < 128) {
                int c2 = c - 64, h = c2 >> 4, d = c2 & 15;
                Kp[((size_t)h * N + row) * 16 + d] = f2bf(v);
            } else {
                int c2 = c - 128, h = c2 >> 4, d = c2 & 15;
                Vp[((size_t)h * 16 + d) * N + row] = f2bf(v);
            }
        }
    }
}

// ---------------- GCN aggregation via CSR gather ----------------
__global__ __launch_bounds__(256) void agg_relu64_kernel(const int* __restrict__ rowstart,
        const int* __restrict__ csr_src, const float* __restrict__ csr_norm,
        const float* __restrict__ dis, const float* __restrict__ H,
        const float* __restrict__ bias, float* __restrict__ out) {
    int node = (blockIdx.x * blockDim.x + threadIdx.x) >> 6;
    int lane = threadIdx.x & 63;
    if (node >= N) return;
    float di = dis[node];
    float acc = di * di * H[(size_t)node * 64 + lane];
    int j = rowstart[node], je = rowstart[node + 1];
    for (; j + 4 <= je; j += 4) {
        int   s0 = csr_src[j],  s1 = csr_src[j + 1],  s2 = csr_src[j + 2],  s3 = csr_src[j + 3];
        float n0 = csr_norm[j], n1 = csr_norm[j + 1], n2 = csr_norm[j + 2], n3 = csr_norm[j + 3];
        acc += n0 * H[(size_t)s0 * 64 + lane];
        acc += n1 * H[(size_t)s1 * 64 + lane];
        acc += n2 * H[(size_t)s2 * 64 + lane];
        acc += n3 * H[(size_t)s3 * 64 + lane];
    }
    for (; j < je; ++j) acc += csr_norm[j] * H[(size_t)csr_src[j] * 64 + lane];
    out[(size_t)node * 64 + lane] = fmaxf(acc + bias[lane], 0.0f);
}

// FD=86: one wave per node, dual accumulators (f=lane, f=64+lane for lane<22)
__global__ __launch_bounds__(256) void agg86_kernel(const int* __restrict__ rowstart,
        const int* __restrict__ csr_src, const float* __restrict__ csr_norm,
        const float* __restrict__ dis, const float* __restrict__ H,
        float* __restrict__ out) {
    int node = (blockIdx.x * blockDim.x + threadIdx.x) >> 6;
    int lane = threadIdx.x & 63;
    if (node >= N) return;
    bool hi = lane < (OUTF - 64);
    float di = dis[node];
    const float* Hn = H + (size_t)node * OUTF;
    float acc0 = di * di * Hn[lane];
    float acc1 = hi ? di * di * Hn[64 + lane] : 0.0f;
    int j = rowstart[node], je = rowstart[node + 1];
    for (; j + 2 <= je; j += 2) {
        int   s0 = csr_src[j],  s1 = csr_src[j + 1];
        float n0 = csr_norm[j], n1 = csr_norm[j + 1];
        const float* H0 = H + (size_t)s0 * OUTF;
        const float* H1 = H + (size_t)s1 * OUTF;
        acc0 += n0 * H0[lane];
        acc1 += hi ? n0 * H0[64 + lane] : 0.0f;
        acc0 += n1 * H1[lane];
        acc1 += hi ? n1 * H1[64 + lane] : 0.0f;
    }
    if (j < je) {
        float n0 = csr_norm[j];
        const float* H0 = H + (size_t)csr_src[j] * OUTF;
        acc0 += n0 * H0[lane];
        acc1 += hi ? n0 * H0[64 + lane] : 0.0f;
    }
    out[(size_t)node * OUTF + lane] = acc0;
    if (hi) out[(size_t)node * OUTF + 64 + lane] = acc1;
}

// ---------------- MFMA flash attention: LDS-free K/V (bf16 packed in L2) ----------------
// grid (N/64, HEADS, NSPLIT); 256 threads = 4 waves; wave = 16 queries x 512 keys.
__global__ __launch_bounds__(256) void attn_mfma_kernel(const unsigned short* __restrict__ Qp,
        const unsigned short* __restrict__ Kp, const unsigned short* __restrict__ Vp,
        float* __restrict__ o_part, float* __restrict__ l_part) {
    __shared__ __align__(16) unsigned short Plds[4 * 16 * 40];  // per-wave P roundtrip

    const int h  = blockIdx.y;
    const int sp = blockIdx.z;
    const int k0 = sp * KEYS;
    const int tid = threadIdx.x;
    const int lane = tid & 63, wv = tid >> 6;
    const int q15 = lane & 15, quad = lane >> 4;

    const int qbase = blockIdx.x * 64 + wv * 16;
    short8 qf = {};
    if (quad < 2)
        qf = *(const short8*)&Qp[((size_t)h * N + qbase + q15) * 16 + quad * 8];

    f32x4 O = {0.f, 0.f, 0.f, 0.f};
    float l = 0.f;
    unsigned short* Pw = &Plds[wv * 640];
    const unsigned short* Kh = Kp + (size_t)h * N * 16;
    const unsigned short* Vh = Vp + ((size_t)h * 16 + q15) * N + k0;

#pragma unroll 2
    for (int ch = 0; ch < KEYS / 32; ++ch) {
#pragma unroll
        for (int t = 0; t < 2; ++t) {
            short8 kf = {};
            if (quad < 2)
                kf = *(const short8*)&Kh[(size_t)(k0 + ch * 32 + t * 16 + q15) * 16 + quad * 8];
            f32x4 zero = {0.f, 0.f, 0.f, 0.f};
            f32x4 s = __builtin_amdgcn_mfma_f32_16x16x32_bf16(kf, qf, zero, 0, 0, 0);
            // C-layout: col=query=lane&15, row=key=quad*4+reg
            float p0 = __expf(s[0]), p1 = __expf(s[1]), p2 = __expf(s[2]), p3 = __expf(s[3]);
            l += p0 + p1 + p2 + p3;
            ushort4 pu;
            pu.x = f2bf(p0); pu.y = f2bf(p1); pu.z = f2bf(p2); pu.w = f2bf(p3);
            *(ushort4*)&Pw[q15 * 40 + t * 16 + quad * 4] = pu;
        }
        asm volatile("s_waitcnt lgkmcnt(0)" ::: "memory");
        short8 pf = *(const short8*)&Pw[q15 * 40 + quad * 8];        // A: m=query, k=key
        short8 vf = *(const short8*)&Vh[ch * 32 + quad * 8];         // B: n=dh,    k=key
        O = __builtin_amdgcn_mfma_f32_16x16x32_bf16(pf, vf, O, 0, 0, 0);
    }

    l += __shfl_xor(l, 16);
    l += __shfl_xor(l, 32);
    if (lane < 16)
        l_part[((size_t)h * N + qbase + q15) * NSPLIT + sp] = l;
#pragma unroll
    for (int r = 0; r < 4; ++r) {
        int query = qbase + quad * 4 + r;
        o_part[(((size_t)h * N + query) * NSPLIT + sp) * 16 + q15] = O[r];
    }
}

// element-parallel combine: one thread per (head*N, d4)
__global__ __launch_bounds__(256) void combine_kernel(const float4* __restrict__ o_part,
        const float* __restrict__ l_part, float* __restrict__ o) {
    int g = blockIdx.x * blockDim.x + threadIdx.x;
    if (g >= HEADS * N * 4) return;
    int t = g >> 2, d4 = g & 3;
    int h = t / N, qi = t - h * N;
    const float* lp = l_part + (size_t)t * NSPLIT;
    float L = 0.f;
#pragma unroll
    for (int s = 0; s < NSPLIT; ++s) L += lp[s];
    float4 acc = make_float4(0.f, 0.f, 0.f, 0.f);
    const float4* op = o_part + (size_t)t * NSPLIT * 4 + d4;
#pragma unroll
    for (int s = 0; s < NSPLIT; ++s) {
        float4 v = op[s * 4];
        acc.x += v.x; acc.y += v.y; acc.z += v.z; acc.w += v.w;
    }
    float inv = 1.0f / L;
    ((float4*)(o + (size_t)qi * 64 + h * 16))[d4] =
        make_float4(acc.x * inv, acc.y * inv, acc.z * inv, acc.w * inv);
}

// ---------------- pooled mean per graph (two-phase) ----------------
__global__ void pool_partial_kernel(const float* __restrict__ h2, const int* __restrict__ batch,
                                    float* __restrict__ pbuf, int* __restrict__ pcnt) {
    int b = blockIdx.x, c = blockIdx.y;
    int lo = 0, hi = N;
    while (lo < hi) { int mid = (lo + hi) >> 1; if (batch[mid] < b) lo = mid + 1; else hi = mid; }
    int start = lo;
    lo = start; hi = N;
    while (lo < hi) { int mid = (lo + hi) >> 1; if (batch[mid] < b + 1) lo = mid + 1; else hi = mid; }
    int end = lo;
    int len = end - start;
    int cs = start + (int)((long long)len * c / PC);
    int ce = start + (int)((long long)len * (c + 1) / PC);
    int f = threadIdx.x;
    if (f == 0) pcnt[b * PC + c] = ce - cs;
    if (f >= OUTF) return;
    float acc = 0.f;
    for (int i = cs; i < ce; ++i) acc += h2[(size_t)i * OUTF + f];
    pbuf[(b * PC + c) * OUTF + f] = acc;
}

__global__ void pool_final_kernel(const float* __restrict__ pbuf, const int* __restrict__ pcnt,
                                  const float* __restrict__ b2, float* __restrict__ out) {
    int b = blockIdx.x, f = threadIdx.x;
    if (f >= OUTF) return;
    float acc = 0.f;
    int cnt = 0;
#pragma unroll
    for (int c = 0; c < PC; ++c) {
        acc += pbuf[(b * PC + c) * OUTF + f];
        cnt += pcnt[b * PC + c];
    }
    out[b * OUTF + f] = cnt > 0 ? acc / (float)cnt + b2[f] : 0.0f;
}

extern "C" void kernel_launch(void* const* d_in, const int* in_sizes, int n_in,
                              void* d_out, int out_size, void* d_ws, size_t ws_size,
                              hipStream_t stream) {
    const float* x     = (const float*)d_in[0];
    const int*   ei    = (const int*)  d_in[1];
    const float* ea    = (const float*)d_in[2];
    const int*   batch = (const int*)  d_in[3];
    const float* W1    = (const float*)d_in[4];
    const float* b1    = (const float*)d_in[5];
    const float* Win   = (const float*)d_in[6];
    const float* b_in  = (const float*)d_in[7];
    const float* Wout  = (const float*)d_in[8];
    const float* b_out = (const float*)d_in[9];
    const float* W2    = (const float*)d_in[10];
    const float* b2    = (const float*)d_in[11];
    float* out = (float*)d_out;
    float* ws  = (float*)d_ws;

    float* deg      = ws + OFF_DEG;
    int*   counts   = (int*)(ws + OFF_CNT);
    int*   cursor   = (int*)(ws + OFF_CUR);
    float* dis      = ws + OFF_DIS;
    int*   rowstart = (int*)(ws + OFF_ROW);
    int*   csr_src  = (int*)(ws + OFF_CSRC);
    float* csr_norm = ws + OFF_CNRM;
    float* bufA     = ws + OFF_BUFA;
    float* bufB     = ws + OFF_BUFB;
    unsigned short* Qp = (unsigned short*)(ws + OFF_QP);
    unsigned short* Kp = (unsigned short*)(ws + OFF_KP);
    unsigned short* Vp = (unsigned short*)(ws + OFF_VP);
    float* h2pre    = ws + OFF_H2PRE;
    float* h2agg    = ws + OFF_H2AGG;
    float* opart    = ws + OFF_OPART;
    float* lpart    = ws + OFF_LPART;
    float* pbuf     = ws + OFF_PBUF;
    int*   pcnt     = (int*)(ws + OFF_PCNT);

    // CSR build (deg/counts/cursor zeroed in one memset)
    hipMemsetAsync(deg, 0, (size_t)3 * N * 4, stream);
    hist_kernel<<<(E + 255) / 256, 256, 0, stream>>>(ei, ea, deg, counts);
    scan_dis_kernel<<<1, 256, 0, stream>>>(counts, deg, rowstart, dis);
    fill_kernel<<<(E + 255) / 256, 256, 0, stream>>>(ei, ea, dis, rowstart, cursor,
                                                     csr_src, csr_norm);

    // GCN1: xW1 -> gather-aggregate (+b1, ReLU fused)
    gemm_kernel<64, 64, 2><<<N / 16, 256, 0, stream>>>(x, W1, nullptr, bufA);
    agg_relu64_kernel<<<(N * 64) / 256, 256, 0, stream>>>(rowstart, csr_src, csr_norm, dis,
                                                          bufA, b1, bufB);

    // QKV projection with fused bf16 pack (Qp scaled, Kp, Vp transposed)
    gemm_qkv_kernel<<<N / 16, 256, 0, stream>>>(bufB, Win, b_in, Qp, Kp, Vp);

    // MFMA flash attention (LDS-free K/V) + combine into bufB (=o, [N,64])
    attn_mfma_kernel<<<dim3(N / 64, HEADS, NSPLIT), 256, 0, stream>>>(Qp, Kp, Vp, opart, lpart);
    combine_kernel<<<(HEADS * N * 4) / 256, 256, 0, stream>>>((const float4*)opart, lpart, bufB);

    // output projection: bufA = o @ Wout^T + b_out
    gemm_kernel<64, 64, 2><<<N / 16, 256, 0, stream>>>(bufB, Wout, b_out, bufA);

    // GCN2: h2pre = bufA @ W2^T, gather-aggregate (bias folded into pool)
    gemm_kernel<86, 96, 3><<<N / 16, 256, 0, stream>>>(bufA, W2, nullptr, h2pre);
    agg86_kernel<<<(N * 64) / 256, 256, 0, stream>>>(rowstart, csr_src, csr_norm, dis,
                                                     h2pre, h2agg);

    // pooled mean + b2 (two-phase)
    pool_partial_kernel<<<dim3(NB, PC), 128, 0, stream>>>(h2agg, batch, pbuf, pcnt);
    pool_final_kernel<<<NB, 128, 0, stream>>>(pbuf, pcnt, b2, out);
}